// Round 1
// baseline (12896.416 us; speedup 1.0000x reference)
//
#include <hip/hip_runtime.h>

#define N_USERS 200000
#define N_ITEMS 100000
#define N_NODES 300000
#define EMB     64
#define N_EDGES 5000000

// ---------------------------------------------------------------------------
// init: x = concat(emb_user, emb_item); out = x  (layer-sum seeded with x0)
// float4 over 4.8M elements
// ---------------------------------------------------------------------------
__global__ __launch_bounds__(256) void init_kernel(
    const float* __restrict__ user, const float* __restrict__ item,
    float* __restrict__ x, float* __restrict__ out)
{
    const int nu4 = N_USERS * EMB / 4;   // 3,200,000
    const int nt4 = N_NODES * EMB / 4;   // 4,800,000
    int i = blockIdx.x * blockDim.x + threadIdx.x;
    if (i >= nt4) return;
    float4 v = (i < nu4) ? reinterpret_cast<const float4*>(user)[i]
                         : reinterpret_cast<const float4*>(item)[i - nu4];
    reinterpret_cast<float4*>(x)[i]   = v;
    reinterpret_cast<float4*>(out)[i] = v;
}

// ---------------------------------------------------------------------------
// SpMM: y[row[e], :] += val[e] * x[col[e], :]
// 16 threads per edge; each thread handles 4 contiguous dims (float4 gather,
// 4 hardware fp32 atomics). Gather+scatter are 256B-contiguous per edge group.
// ---------------------------------------------------------------------------
__global__ __launch_bounds__(256) void spmm_kernel(
    const float* __restrict__ x, const float* __restrict__ val,
    const int* __restrict__ row, const int* __restrict__ col,
    float* __restrict__ y)
{
    int t = blockIdx.x * blockDim.x + threadIdx.x;
    int e = t >> 4;
    if (e >= N_EDGES) return;
    int d = (t & 15) * 4;

    int   r = row[e];
    int   c = col[e];
    float v = val[e];

    float4 xv = *reinterpret_cast<const float4*>(x + c * EMB + d);
    float* yp = y + r * EMB + d;
    // hardware global_atomic_add_f32 (no CAS loop regardless of compile flags)
    unsafeAtomicAdd(yp + 0, v * xv.x);
    unsafeAtomicAdd(yp + 1, v * xv.y);
    unsafeAtomicAdd(yp + 2, v * xv.z);
    unsafeAtomicAdd(yp + 3, v * xv.w);
}

// ---------------------------------------------------------------------------
// out = (out + xl) * scale   (scale = 1.0 mid-layers, 0.25 on the last)
// ---------------------------------------------------------------------------
__global__ __launch_bounds__(256) void addscale_kernel(
    const float* __restrict__ xl, float* __restrict__ out, float scale)
{
    const int nt4 = N_NODES * EMB / 4;
    int i = blockIdx.x * blockDim.x + threadIdx.x;
    if (i >= nt4) return;
    float4 a = reinterpret_cast<float4*>(out)[i];
    float4 b = reinterpret_cast<const float4*>(xl)[i];
    a.x = (a.x + b.x) * scale;
    a.y = (a.y + b.y) * scale;
    a.z = (a.z + b.z) * scale;
    a.w = (a.w + b.w) * scale;
    reinterpret_cast<float4*>(out)[i] = a;
}

extern "C" void kernel_launch(void* const* d_in, const int* in_sizes, int n_in,
                              void* d_out, int out_size, void* d_ws, size_t ws_size,
                              hipStream_t stream) {
    const float* emb_user = (const float*)d_in[0];
    const float* emb_item = (const float*)d_in[1];
    const float* edge_val = (const float*)d_in[2];
    const int*   edge_row = (const int*)d_in[3];
    const int*   edge_col = (const int*)d_in[4];
    float* out = (float*)d_out;

    const size_t node_elems = (size_t)N_NODES * EMB;           // 19.2M floats
    float* bufA = (float*)d_ws;
    float* bufB = bufA + node_elems;

    const int nt4 = N_NODES * EMB / 4;                         // 4.8M float4
    const int ew_blocks = (N_EDGES * 16 + 255) / 256;          // 312,500
    const int el_blocks = (nt4 + 255) / 256;                   // 18,750

    init_kernel<<<el_blocks, 256, 0, stream>>>(emb_user, emb_item, bufA, out);

    float* cur = bufA;
    float* nxt = bufB;
    for (int layer = 0; layer < 3; ++layer) {
        hipMemsetAsync(nxt, 0, node_elems * sizeof(float), stream);
        spmm_kernel<<<ew_blocks, 256, 0, stream>>>(cur, edge_val, edge_row, edge_col, nxt);
        addscale_kernel<<<el_blocks, 256, 0, stream>>>(
            nxt, out, (layer == 2) ? 0.25f : 1.0f);
        float* tmp = cur; cur = nxt; nxt = tmp;
    }
}

// Round 2
// 2089.121 us; speedup vs baseline: 6.1731x; 6.1731x over previous
//
#include <hip/hip_runtime.h>

#define N_USERS 200000
#define N_ITEMS 100000
#define N_NODES 300000
#define EMB     64
#define N_EDGES 5000000

struct alignas(8) Edge { int col; float val; };

// ---------------------------------------------------------------------------
// init: x = concat(emb_user, emb_item); out = x  (layer-sum seeded with x0)
// ---------------------------------------------------------------------------
__global__ __launch_bounds__(256) void init_kernel(
    const float* __restrict__ user, const float* __restrict__ item,
    float* __restrict__ x, float* __restrict__ out)
{
    const int nu4 = N_USERS * EMB / 4;
    const int nt4 = N_NODES * EMB / 4;
    int i = blockIdx.x * blockDim.x + threadIdx.x;
    if (i >= nt4) return;
    float4 v = (i < nu4) ? reinterpret_cast<const float4*>(user)[i]
                         : reinterpret_cast<const float4*>(item)[i - nu4];
    reinterpret_cast<float4*>(x)[i]   = v;
    reinterpret_cast<float4*>(out)[i] = v;
}

// ---------------------------------------------------------------------------
// CSR build step 1: per-row edge counts (int atomics on 1.2 MB array)
// ---------------------------------------------------------------------------
__global__ __launch_bounds__(256) void count_kernel(
    const int* __restrict__ row, int* __restrict__ cnt)
{
    int e = blockIdx.x * blockDim.x + threadIdx.x;
    if (e < N_EDGES) atomicAdd(&cnt[row[e]], 1);
}

// ---------------------------------------------------------------------------
// CSR build step 2: exclusive scan of counts -> start[]; cursor[] = start[].
// Single block, 1024 threads, thread-coarse segments + LDS Hillis-Steele.
// ---------------------------------------------------------------------------
#define SCAN_T 1024
#define SCAN_SEG ((N_NODES + SCAN_T - 1) / SCAN_T)   // 293
__global__ __launch_bounds__(1024) void scan_kernel(
    const int* __restrict__ cnt, int* __restrict__ start, int* __restrict__ cursor)
{
    __shared__ int s[SCAN_T];
    int t  = threadIdx.x;
    int lo = t * SCAN_SEG;       if (lo > N_NODES) lo = N_NODES;
    int hi = lo + SCAN_SEG;      if (hi > N_NODES) hi = N_NODES;
    int sum = 0;
    for (int i = lo; i < hi; ++i) sum += cnt[i];
    s[t] = sum;
    __syncthreads();
    for (int ofs = 1; ofs < SCAN_T; ofs <<= 1) {
        int v = (t >= ofs) ? s[t - ofs] : 0;
        __syncthreads();
        s[t] += v;
        __syncthreads();
    }
    int running = s[t] - sum;    // exclusive prefix of this thread's segment
    for (int i = lo; i < hi; ++i) {
        int c = cnt[i];
        start[i]  = running;
        cursor[i] = running;
        running += c;
    }
    if (t == SCAN_T - 1) start[N_NODES] = running;
}

// ---------------------------------------------------------------------------
// CSR build step 3: scatter edges into row-sorted order.
// After this, cursor[r] == end-of-row-r pointer.
// ---------------------------------------------------------------------------
__global__ __launch_bounds__(256) void scatter_kernel(
    const int* __restrict__ row, const int* __restrict__ col,
    const float* __restrict__ val, int* __restrict__ cursor,
    Edge* __restrict__ packed)
{
    int e = blockIdx.x * blockDim.x + threadIdx.x;
    if (e >= N_EDGES) return;
    int r   = row[e];
    int pos = atomicAdd(&cursor[r], 1);
    Edge ed; ed.col = col[e]; ed.val = val[e];
    packed[pos] = ed;
}

// ---------------------------------------------------------------------------
// CSR SpMM, fused with layer-sum update:
//   y[r,:] = sum_j val_j * x[col_j,:];   out[r,:] = (out[r,:] + y[r,:]) * scale
// 16 lanes per row, 4 dims per lane, accumulate in registers, no atomics.
// ---------------------------------------------------------------------------
__global__ __launch_bounds__(256) void spmm_csr_kernel(
    const float* __restrict__ x, const Edge* __restrict__ packed,
    const int* __restrict__ start, const int* __restrict__ endp,
    float* __restrict__ y, float* __restrict__ out, float scale)
{
    int g = blockIdx.x * (256 / 16) + (threadIdx.x >> 4);
    if (g >= N_NODES) return;
    int d = (threadIdx.x & 15) * 4;

    int beg = start[g];
    int e   = endp[g];
    float4 acc = {0.f, 0.f, 0.f, 0.f};
    for (int j = beg; j < e; ++j) {
        Edge ed = packed[j];
        float4 xv = *reinterpret_cast<const float4*>(x + (size_t)ed.col * EMB + d);
        acc.x += ed.val * xv.x;
        acc.y += ed.val * xv.y;
        acc.z += ed.val * xv.z;
        acc.w += ed.val * xv.w;
    }
    *reinterpret_cast<float4*>(y + (size_t)g * EMB + d) = acc;

    float4 o = *reinterpret_cast<float4*>(out + (size_t)g * EMB + d);
    o.x = (o.x + acc.x) * scale;
    o.y = (o.y + acc.y) * scale;
    o.z = (o.z + acc.z) * scale;
    o.w = (o.w + acc.w) * scale;
    *reinterpret_cast<float4*>(out + (size_t)g * EMB + d) = o;
}

// ---------------------------------------------------------------------------
// Fallback path (round-1): edge-parallel atomics. Used only if ws too small.
// ---------------------------------------------------------------------------
__global__ __launch_bounds__(256) void spmm_atomic_kernel(
    const float* __restrict__ x, const float* __restrict__ val,
    const int* __restrict__ row, const int* __restrict__ col,
    float* __restrict__ y)
{
    int t = blockIdx.x * blockDim.x + threadIdx.x;
    int e = t >> 4;
    if (e >= N_EDGES) return;
    int d = (t & 15) * 4;
    int   r = row[e];
    int   c = col[e];
    float v = val[e];
    float4 xv = *reinterpret_cast<const float4*>(x + c * EMB + d);
    float* yp = y + r * EMB + d;
    unsafeAtomicAdd(yp + 0, v * xv.x);
    unsafeAtomicAdd(yp + 1, v * xv.y);
    unsafeAtomicAdd(yp + 2, v * xv.z);
    unsafeAtomicAdd(yp + 3, v * xv.w);
}

__global__ __launch_bounds__(256) void addscale_kernel(
    const float* __restrict__ xl, float* __restrict__ out, float scale)
{
    const int nt4 = N_NODES * EMB / 4;
    int i = blockIdx.x * blockDim.x + threadIdx.x;
    if (i >= nt4) return;
    float4 a = reinterpret_cast<float4*>(out)[i];
    float4 b = reinterpret_cast<const float4*>(xl)[i];
    a.x = (a.x + b.x) * scale;
    a.y = (a.y + b.y) * scale;
    a.z = (a.z + b.z) * scale;
    a.w = (a.w + b.w) * scale;
    reinterpret_cast<float4*>(out)[i] = a;
}

extern "C" void kernel_launch(void* const* d_in, const int* in_sizes, int n_in,
                              void* d_out, int out_size, void* d_ws, size_t ws_size,
                              hipStream_t stream) {
    const float* emb_user = (const float*)d_in[0];
    const float* emb_item = (const float*)d_in[1];
    const float* edge_val = (const float*)d_in[2];
    const int*   edge_row = (const int*)d_in[3];
    const int*   edge_col = (const int*)d_in[4];
    float* out = (float*)d_out;

    const size_t node_elems = (size_t)N_NODES * EMB;        // 19.2M floats
    char* ws = (char*)d_ws;

    // workspace layout
    const size_t off_bufA   = 0;
    const size_t off_bufB   = off_bufA + node_elems * sizeof(float);      // 76.8 MB
    const size_t off_packed = off_bufB + node_elems * sizeof(float);      // 153.6 MB
    const size_t off_start  = off_packed + (size_t)N_EDGES * sizeof(Edge);// 193.6 MB
    const size_t off_cursor = off_start + (N_NODES + 4) * sizeof(int);
    const size_t off_cnt    = off_cursor + N_NODES * sizeof(int);
    const size_t needed     = off_cnt + N_NODES * sizeof(int);            // ~197.2 MB

    float* bufA   = (float*)(ws + off_bufA);
    float* bufB   = (float*)(ws + off_bufB);

    const int nt4       = N_NODES * EMB / 4;
    const int el_blocks = (nt4 + 255) / 256;
    const int e_blocks  = (N_EDGES + 255) / 256;

    init_kernel<<<el_blocks, 256, 0, stream>>>(emb_user, emb_item, bufA, out);

    if (ws_size >= needed) {
        // ---- CSR path ----
        Edge* packed  = (Edge*)(ws + off_packed);
        int*  start   = (int*) (ws + off_start);
        int*  cursor  = (int*) (ws + off_cursor);
        int*  cnt     = (int*) (ws + off_cnt);

        hipMemsetAsync(cnt, 0, N_NODES * sizeof(int), stream);
        count_kernel<<<e_blocks, 256, 0, stream>>>(edge_row, cnt);
        scan_kernel<<<1, SCAN_T, 0, stream>>>(cnt, start, cursor);
        scatter_kernel<<<e_blocks, 256, 0, stream>>>(edge_row, edge_col, edge_val,
                                                     cursor, packed);

        const int row_blocks = (N_NODES + 15) / 16;          // 16 rows / block
        float* cur = bufA;
        float* nxt = bufB;
        for (int layer = 0; layer < 3; ++layer) {
            spmm_csr_kernel<<<row_blocks, 256, 0, stream>>>(
                cur, packed, start, cursor, nxt, out,
                (layer == 2) ? 0.25f : 1.0f);
            float* tmp = cur; cur = nxt; nxt = tmp;
        }
    } else {
        // ---- fallback: atomic path (needs only 153.6 MB) ----
        const int ew_blocks = (N_EDGES * 16 + 255) / 256;
        float* cur = bufA;
        float* nxt = bufB;
        for (int layer = 0; layer < 3; ++layer) {
            hipMemsetAsync(nxt, 0, node_elems * sizeof(float), stream);
            spmm_atomic_kernel<<<ew_blocks, 256, 0, stream>>>(
                cur, edge_val, edge_row, edge_col, nxt);
            addscale_kernel<<<el_blocks, 256, 0, stream>>>(
                nxt, out, (layer == 2) ? 0.25f : 1.0f);
            float* tmp = cur; cur = nxt; nxt = tmp;
        }
    }
}

// Round 3
// 1432.228 us; speedup vs baseline: 9.0044x; 1.4587x over previous
//
#include <hip/hip_runtime.h>

#define N_USERS 200000
#define N_ITEMS 100000
#define N_NODES 300000
#define EMB     64
#define N_EDGES 5000000

struct alignas(8) Edge { int col; float val; };

// ---------------------------------------------------------------------------
// init: x = concat(emb_user, emb_item); out = x  (layer-sum seeded with x0)
// ---------------------------------------------------------------------------
__global__ __launch_bounds__(256) void init_kernel(
    const float* __restrict__ user, const float* __restrict__ item,
    float* __restrict__ x, float* __restrict__ out)
{
    const int nu4 = N_USERS * EMB / 4;
    const int nt4 = N_NODES * EMB / 4;
    int i = blockIdx.x * blockDim.x + threadIdx.x;
    if (i >= nt4) return;
    float4 v = (i < nu4) ? reinterpret_cast<const float4*>(user)[i]
                         : reinterpret_cast<const float4*>(item)[i - nu4];
    reinterpret_cast<float4*>(x)[i]   = v;
    reinterpret_cast<float4*>(out)[i] = v;
}

// ---------------------------------------------------------------------------
// CSR build step 1: per-row edge counts
// ---------------------------------------------------------------------------
__global__ __launch_bounds__(256) void count_kernel(
    const int* __restrict__ row, int* __restrict__ cnt)
{
    int e = blockIdx.x * blockDim.x + threadIdx.x;
    if (e < N_EDGES) atomicAdd(&cnt[row[e]], 1);
}

// ---------------------------------------------------------------------------
// CSR build step 2: hierarchical exclusive scan (3 phases, full-GPU parallel)
// ---------------------------------------------------------------------------
#define SCAN_BLOCKS ((N_NODES + 255) / 256)   // 1172

// 2a: per-block sums of cnt
__global__ __launch_bounds__(256) void bsum_kernel(
    const int* __restrict__ cnt, int* __restrict__ bsum)
{
    __shared__ int s[256];
    int t = threadIdx.x;
    int i = blockIdx.x * 256 + t;
    s[t] = (i < N_NODES) ? cnt[i] : 0;
    __syncthreads();
    for (int ofs = 128; ofs > 0; ofs >>= 1) {
        if (t < ofs) s[t] += s[t + ofs];
        __syncthreads();
    }
    if (t == 0) bsum[blockIdx.x] = s[0];
}

// 2b: single-block exclusive scan over 1172 block sums (tiny)
__global__ __launch_bounds__(1024) void bscan_kernel(
    const int* __restrict__ bsum, int* __restrict__ bpre)
{
    __shared__ int s[1024];
    const int SEG = (SCAN_BLOCKS + 1023) / 1024;   // 2
    int t  = threadIdx.x;
    int lo = t * SEG;
    int hi = lo + SEG; if (hi > SCAN_BLOCKS) hi = SCAN_BLOCKS;
    int sum = 0;
    for (int i = lo; i < hi && i < SCAN_BLOCKS; ++i) sum += bsum[i];
    s[t] = sum;
    __syncthreads();
    for (int ofs = 1; ofs < 1024; ofs <<= 1) {
        int v = (t >= ofs) ? s[t - ofs] : 0;
        __syncthreads();
        s[t] += v;
        __syncthreads();
    }
    int running = s[t] - sum;
    for (int i = lo; i < hi && i < SCAN_BLOCKS; ++i) {
        bpre[i] = running;
        running += bsum[i];
    }
}

// 2c: per-block local scan + block offset -> start[], cursor[]
__global__ __launch_bounds__(256) void scan_apply_kernel(
    const int* __restrict__ cnt, const int* __restrict__ bpre,
    int* __restrict__ start, int* __restrict__ cursor)
{
    __shared__ int s[256];
    int t = threadIdx.x;
    int i = blockIdx.x * 256 + t;
    int v = (i < N_NODES) ? cnt[i] : 0;
    s[t] = v;
    __syncthreads();
    for (int ofs = 1; ofs < 256; ofs <<= 1) {
        int w = (t >= ofs) ? s[t - ofs] : 0;
        __syncthreads();
        s[t] += w;
        __syncthreads();
    }
    int excl = s[t] - v + bpre[blockIdx.x];
    if (i < N_NODES) {
        start[i]  = excl;
        cursor[i] = excl;
    }
    if (blockIdx.x == 0 && t == 0) start[N_NODES] = N_EDGES;
}

// ---------------------------------------------------------------------------
// CSR build step 3: scatter edges into row-sorted order.
// After this, cursor[r] == end-of-row-r pointer.
// ---------------------------------------------------------------------------
__global__ __launch_bounds__(256) void scatter_kernel(
    const int* __restrict__ row, const int* __restrict__ col,
    const float* __restrict__ val, int* __restrict__ cursor,
    Edge* __restrict__ packed)
{
    int e = blockIdx.x * blockDim.x + threadIdx.x;
    if (e >= N_EDGES) return;
    int r   = row[e];
    int pos = atomicAdd(&cursor[r], 1);
    Edge ed; ed.col = col[e]; ed.val = val[e];
    packed[pos] = ed;
}

// ---------------------------------------------------------------------------
// CSR SpMM, fused with layer-sum update:
//   y[r,:] = sum_j val_j * x[col_j,:];   out[r,:] = (out[r,:] + y[r,:]) * scale
// 16 lanes per row, 4 dims per lane, accumulate in registers, no atomics.
// ---------------------------------------------------------------------------
__global__ __launch_bounds__(256) void spmm_csr_kernel(
    const float* __restrict__ x, const Edge* __restrict__ packed,
    const int* __restrict__ start, const int* __restrict__ endp,
    float* __restrict__ y, float* __restrict__ out, float scale)
{
    int g = blockIdx.x * (256 / 16) + (threadIdx.x >> 4);
    if (g >= N_NODES) return;
    int d = (threadIdx.x & 15) * 4;

    int beg = start[g];
    int e   = endp[g];
    float4 acc = {0.f, 0.f, 0.f, 0.f};
    for (int j = beg; j < e; ++j) {
        Edge ed = packed[j];
        float4 xv = *reinterpret_cast<const float4*>(x + (size_t)ed.col * EMB + d);
        acc.x += ed.val * xv.x;
        acc.y += ed.val * xv.y;
        acc.z += ed.val * xv.z;
        acc.w += ed.val * xv.w;
    }
    *reinterpret_cast<float4*>(y + (size_t)g * EMB + d) = acc;

    float4 o = *reinterpret_cast<float4*>(out + (size_t)g * EMB + d);
    o.x = (o.x + acc.x) * scale;
    o.y = (o.y + acc.y) * scale;
    o.z = (o.z + acc.z) * scale;
    o.w = (o.w + acc.w) * scale;
    *reinterpret_cast<float4*>(out + (size_t)g * EMB + d) = o;
}

// ---------------------------------------------------------------------------
// Fallback path: edge-parallel atomics. Used only if ws too small for CSR.
// ---------------------------------------------------------------------------
__global__ __launch_bounds__(256) void spmm_atomic_kernel(
    const float* __restrict__ x, const float* __restrict__ val,
    const int* __restrict__ row, const int* __restrict__ col,
    float* __restrict__ y)
{
    int t = blockIdx.x * blockDim.x + threadIdx.x;
    int e = t >> 4;
    if (e >= N_EDGES) return;
    int d = (t & 15) * 4;
    int   r = row[e];
    int   c = col[e];
    float v = val[e];
    float4 xv = *reinterpret_cast<const float4*>(x + c * EMB + d);
    float* yp = y + r * EMB + d;
    unsafeAtomicAdd(yp + 0, v * xv.x);
    unsafeAtomicAdd(yp + 1, v * xv.y);
    unsafeAtomicAdd(yp + 2, v * xv.z);
    unsafeAtomicAdd(yp + 3, v * xv.w);
}

__global__ __launch_bounds__(256) void addscale_kernel(
    const float* __restrict__ xl, float* __restrict__ out, float scale)
{
    const int nt4 = N_NODES * EMB / 4;
    int i = blockIdx.x * blockDim.x + threadIdx.x;
    if (i >= nt4) return;
    float4 a = reinterpret_cast<float4*>(out)[i];
    float4 b = reinterpret_cast<const float4*>(xl)[i];
    a.x = (a.x + b.x) * scale;
    a.y = (a.y + b.y) * scale;
    a.z = (a.z + b.z) * scale;
    a.w = (a.w + b.w) * scale;
    reinterpret_cast<float4*>(out)[i] = a;
}

extern "C" void kernel_launch(void* const* d_in, const int* in_sizes, int n_in,
                              void* d_out, int out_size, void* d_ws, size_t ws_size,
                              hipStream_t stream) {
    const float* emb_user = (const float*)d_in[0];
    const float* emb_item = (const float*)d_in[1];
    const float* edge_val = (const float*)d_in[2];
    const int*   edge_row = (const int*)d_in[3];
    const int*   edge_col = (const int*)d_in[4];
    float* out = (float*)d_out;

    const size_t node_elems = (size_t)N_NODES * EMB;        // 19.2M floats
    char* ws = (char*)d_ws;

    // workspace layout
    const size_t off_bufA   = 0;
    const size_t off_bufB   = off_bufA + node_elems * sizeof(float);      // 76.8 MB
    const size_t off_packed = off_bufB + node_elems * sizeof(float);      // 153.6 MB
    const size_t off_start  = off_packed + (size_t)N_EDGES * sizeof(Edge);// 193.6 MB
    const size_t off_cursor = off_start + (N_NODES + 4) * sizeof(int);
    const size_t off_cnt    = off_cursor + N_NODES * sizeof(int);
    const size_t off_bsum   = off_cnt + N_NODES * sizeof(int);
    const size_t off_bpre   = off_bsum + SCAN_BLOCKS * sizeof(int);
    const size_t needed     = off_bpre + SCAN_BLOCKS * sizeof(int);       // ~197.2 MB

    float* bufA = (float*)(ws + off_bufA);
    float* bufB = (float*)(ws + off_bufB);

    const int nt4       = N_NODES * EMB / 4;
    const int el_blocks = (nt4 + 255) / 256;
    const int e_blocks  = (N_EDGES + 255) / 256;

    init_kernel<<<el_blocks, 256, 0, stream>>>(emb_user, emb_item, bufA, out);

    if (ws_size >= needed) {
        // ---- CSR path ----
        Edge* packed = (Edge*)(ws + off_packed);
        int*  start  = (int*) (ws + off_start);
        int*  cursor = (int*) (ws + off_cursor);
        int*  cnt    = (int*) (ws + off_cnt);
        int*  bsum   = (int*) (ws + off_bsum);
        int*  bpre   = (int*) (ws + off_bpre);

        hipMemsetAsync(cnt, 0, N_NODES * sizeof(int), stream);
        count_kernel<<<e_blocks, 256, 0, stream>>>(edge_row, cnt);
        bsum_kernel<<<SCAN_BLOCKS, 256, 0, stream>>>(cnt, bsum);
        bscan_kernel<<<1, 1024, 0, stream>>>(bsum, bpre);
        scan_apply_kernel<<<SCAN_BLOCKS, 256, 0, stream>>>(cnt, bpre, start, cursor);
        scatter_kernel<<<e_blocks, 256, 0, stream>>>(edge_row, edge_col, edge_val,
                                                     cursor, packed);

        const int row_blocks = (N_NODES + 15) / 16;          // 16 rows / block
        float* cur = bufA;
        float* nxt = bufB;
        for (int layer = 0; layer < 3; ++layer) {
            spmm_csr_kernel<<<row_blocks, 256, 0, stream>>>(
                cur, packed, start, cursor, nxt, out,
                (layer == 2) ? 0.25f : 1.0f);
            float* tmp = cur; cur = nxt; nxt = tmp;
        }
    } else {
        // ---- fallback: atomic path (needs only 153.6 MB) ----
        const int ew_blocks = (N_EDGES * 16 + 255) / 256;
        float* cur = bufA;
        float* nxt = bufB;
        for (int layer = 0; layer < 3; ++layer) {
            hipMemsetAsync(nxt, 0, node_elems * sizeof(float), stream);
            spmm_atomic_kernel<<<ew_blocks, 256, 0, stream>>>(
                cur, edge_val, edge_row, edge_col, nxt);
            addscale_kernel<<<el_blocks, 256, 0, stream>>>(
                nxt, out, (layer == 2) ? 0.25f : 1.0f);
            float* tmp = cur; cur = nxt; nxt = tmp;
        }
    }
}

// Round 4
// 1338.941 us; speedup vs baseline: 9.6318x; 1.0697x over previous
//
#include <hip/hip_runtime.h>

#define N_USERS 200000
#define N_ITEMS 100000
#define N_NODES 300000
#define EMB     64
#define N_EDGES 5000000

struct alignas(8) Edge  { int col; float val; };
struct Edge3 { int row; int col; float val; };   // 12 B staged record

// ---------------------------------------------------------------------------
// init: x = concat(emb_user, emb_item); out = x  (layer-sum seeded with x0)
// ---------------------------------------------------------------------------
__global__ __launch_bounds__(256) void init_kernel(
    const float* __restrict__ user, const float* __restrict__ item,
    float* __restrict__ x, float* __restrict__ out)
{
    const int nu4 = N_USERS * EMB / 4;
    const int nt4 = N_NODES * EMB / 4;
    int i = blockIdx.x * blockDim.x + threadIdx.x;
    if (i >= nt4) return;
    float4 v = (i < nu4) ? reinterpret_cast<const float4*>(user)[i]
                         : reinterpret_cast<const float4*>(item)[i - nu4];
    reinterpret_cast<float4*>(x)[i]   = v;
    reinterpret_cast<float4*>(out)[i] = v;
}

// ---------------------------------------------------------------------------
// CSR build step 1: per-row edge counts
// ---------------------------------------------------------------------------
__global__ __launch_bounds__(256) void count_kernel(
    const int* __restrict__ row, int* __restrict__ cnt)
{
    int e = blockIdx.x * blockDim.x + threadIdx.x;
    if (e < N_EDGES) atomicAdd(&cnt[row[e]], 1);
}

// ---------------------------------------------------------------------------
// CSR build step 2: hierarchical exclusive scan (3 phases, full-GPU parallel)
// ---------------------------------------------------------------------------
#define SCAN_BLOCKS ((N_NODES + 255) / 256)   // 1172

__global__ __launch_bounds__(256) void bsum_kernel(
    const int* __restrict__ cnt, int* __restrict__ bsum)
{
    __shared__ int s[256];
    int t = threadIdx.x;
    int i = blockIdx.x * 256 + t;
    s[t] = (i < N_NODES) ? cnt[i] : 0;
    __syncthreads();
    for (int ofs = 128; ofs > 0; ofs >>= 1) {
        if (t < ofs) s[t] += s[t + ofs];
        __syncthreads();
    }
    if (t == 0) bsum[blockIdx.x] = s[0];
}

__global__ __launch_bounds__(1024) void bscan_kernel(
    const int* __restrict__ bsum, int* __restrict__ bpre)
{
    __shared__ int s[1024];
    const int SEG = (SCAN_BLOCKS + 1023) / 1024;   // 2
    int t  = threadIdx.x;
    int lo = t * SEG;
    int hi = lo + SEG; if (hi > SCAN_BLOCKS) hi = SCAN_BLOCKS;
    int sum = 0;
    for (int i = lo; i < hi && i < SCAN_BLOCKS; ++i) sum += bsum[i];
    s[t] = sum;
    __syncthreads();
    for (int ofs = 1; ofs < 1024; ofs <<= 1) {
        int v = (t >= ofs) ? s[t - ofs] : 0;
        __syncthreads();
        s[t] += v;
        __syncthreads();
    }
    int running = s[t] - sum;
    for (int i = lo; i < hi && i < SCAN_BLOCKS; ++i) {
        bpre[i] = running;
        running += bsum[i];
    }
}

__global__ __launch_bounds__(256) void scan_apply_kernel(
    const int* __restrict__ cnt, const int* __restrict__ bpre,
    int* __restrict__ start, int* __restrict__ cursor)
{
    __shared__ int s[256];
    int t = threadIdx.x;
    int i = blockIdx.x * 256 + t;
    int v = (i < N_NODES) ? cnt[i] : 0;
    s[t] = v;
    __syncthreads();
    for (int ofs = 1; ofs < 256; ofs <<= 1) {
        int w = (t >= ofs) ? s[t - ofs] : 0;
        __syncthreads();
        s[t] += w;
        __syncthreads();
    }
    int excl = s[t] - v + bpre[blockIdx.x];
    if (i < N_NODES) {
        start[i]  = excl;
        cursor[i] = excl;
    }
    if (blockIdx.x == 0 && t == 0) start[N_NODES] = N_EDGES;
}

// ---------------------------------------------------------------------------
// Two-phase bucketed scatter. Bucket = row >> 11 (2048 rows, 147 buckets).
// Bucket base in the CSR layout is just start[b*2048] -> binit copies them.
// ---------------------------------------------------------------------------
#define BSHIFT 11
#define NBUCK  ((N_NODES + (1 << BSHIFT) - 1) >> BSHIFT)   // 147
#define BIN_EPT   16
#define BIN_BLK   256
#define BIN_CHUNK (BIN_BLK * BIN_EPT)                      // 4096 edges/block

__global__ __launch_bounds__(256) void binit_kernel(
    const int* __restrict__ start, int* __restrict__ bcursor)
{
    int t = threadIdx.x;
    if (t < NBUCK) {
        int lo = t << BSHIFT;
        if (lo > N_NODES) lo = N_NODES;
        bcursor[t] = start[lo];
    }
}

// phase 1: bin edges into bucket-contiguous staging (dense, line-friendly)
__global__ __launch_bounds__(256) void bin_kernel(
    const int* __restrict__ row, const int* __restrict__ col,
    const float* __restrict__ val, int* __restrict__ bcursor,
    Edge3* __restrict__ stage)
{
    __shared__ int hist[NBUCK];
    __shared__ int base[NBUCK];
    int t = threadIdx.x;
    long e0 = (long)blockIdx.x * BIN_CHUNK;

    int   r[BIN_EPT]; int c[BIN_EPT]; float v[BIN_EPT];
    for (int k = t; k < NBUCK; k += 256) hist[k] = 0;
    __syncthreads();

    int n = 0;
    #pragma unroll
    for (int k = 0; k < BIN_EPT; ++k) {
        long e = e0 + (long)k * BIN_BLK + t;
        if (e < N_EDGES) {
            r[k] = row[e]; c[k] = col[e]; v[k] = val[e];
            atomicAdd(&hist[r[k] >> BSHIFT], 1);
            n = k + 1;
        }
    }
    __syncthreads();
    for (int k = t; k < NBUCK; k += 256) {
        int h = hist[k];
        base[k] = h ? atomicAdd(&bcursor[k], h) : 0;
        hist[k] = 0;    // reuse as local cursor
    }
    __syncthreads();
    #pragma unroll
    for (int k = 0; k < BIN_EPT; ++k) {
        if (k < n) {
            long e = e0 + (long)k * BIN_BLK + t;
            if (e < N_EDGES) {
                int b   = r[k] >> BSHIFT;
                int pos = base[b] + atomicAdd(&hist[b], 1);
                Edge3 ed; ed.row = r[k]; ed.col = c[k]; ed.val = v[k];
                stage[pos] = ed;
            }
        }
    }
}

// phase 2: per-bucket dense region -> exact CSR position (L2-resident RMW)
__global__ __launch_bounds__(256) void bscatter_kernel(
    const Edge3* __restrict__ stage, int* __restrict__ cursor,
    Edge* __restrict__ packed)
{
    int e = blockIdx.x * blockDim.x + threadIdx.x;
    if (e >= N_EDGES) return;
    Edge3 ed = stage[e];
    int pos = atomicAdd(&cursor[ed.row], 1);
    Edge p; p.col = ed.col; p.val = ed.val;
    packed[pos] = p;
}

// ---------------------------------------------------------------------------
// CSR SpMM, fused with layer-sum update.
// 16 lanes per row, 4 dims per lane, register accumulation, no atomics.
// ---------------------------------------------------------------------------
__global__ __launch_bounds__(256) void spmm_csr_kernel(
    const float* __restrict__ x, const Edge* __restrict__ packed,
    const int* __restrict__ start, const int* __restrict__ endp,
    float* __restrict__ y, float* __restrict__ out, float scale)
{
    int g = blockIdx.x * (256 / 16) + (threadIdx.x >> 4);
    if (g >= N_NODES) return;
    int d = (threadIdx.x & 15) * 4;

    int beg = start[g];
    int e   = endp[g];
    float4 acc = {0.f, 0.f, 0.f, 0.f};
    for (int j = beg; j < e; ++j) {
        Edge ed = packed[j];
        float4 xv = *reinterpret_cast<const float4*>(x + (size_t)ed.col * EMB + d);
        acc.x += ed.val * xv.x;
        acc.y += ed.val * xv.y;
        acc.z += ed.val * xv.z;
        acc.w += ed.val * xv.w;
    }
    *reinterpret_cast<float4*>(y + (size_t)g * EMB + d) = acc;

    float4 o = *reinterpret_cast<float4*>(out + (size_t)g * EMB + d);
    o.x = (o.x + acc.x) * scale;
    o.y = (o.y + acc.y) * scale;
    o.z = (o.z + acc.z) * scale;
    o.w = (o.w + acc.w) * scale;
    *reinterpret_cast<float4*>(out + (size_t)g * EMB + d) = o;
}

// ---------------------------------------------------------------------------
// Fallback path: edge-parallel atomics. Used only if ws too small for CSR.
// ---------------------------------------------------------------------------
__global__ __launch_bounds__(256) void spmm_atomic_kernel(
    const float* __restrict__ x, const float* __restrict__ val,
    const int* __restrict__ row, const int* __restrict__ col,
    float* __restrict__ y)
{
    int t = blockIdx.x * blockDim.x + threadIdx.x;
    int e = t >> 4;
    if (e >= N_EDGES) return;
    int d = (t & 15) * 4;
    int   r = row[e];
    int   c = col[e];
    float v = val[e];
    float4 xv = *reinterpret_cast<const float4*>(x + c * EMB + d);
    float* yp = y + r * EMB + d;
    unsafeAtomicAdd(yp + 0, v * xv.x);
    unsafeAtomicAdd(yp + 1, v * xv.y);
    unsafeAtomicAdd(yp + 2, v * xv.z);
    unsafeAtomicAdd(yp + 3, v * xv.w);
}

__global__ __launch_bounds__(256) void addscale_kernel(
    const float* __restrict__ xl, float* __restrict__ out, float scale)
{
    const int nt4 = N_NODES * EMB / 4;
    int i = blockIdx.x * blockDim.x + threadIdx.x;
    if (i >= nt4) return;
    float4 a = reinterpret_cast<float4*>(out)[i];
    float4 b = reinterpret_cast<const float4*>(xl)[i];
    a.x = (a.x + b.x) * scale;
    a.y = (a.y + b.y) * scale;
    a.z = (a.z + b.z) * scale;
    a.w = (a.w + b.w) * scale;
    reinterpret_cast<float4*>(out)[i] = a;
}

extern "C" void kernel_launch(void* const* d_in, const int* in_sizes, int n_in,
                              void* d_out, int out_size, void* d_ws, size_t ws_size,
                              hipStream_t stream) {
    const float* emb_user = (const float*)d_in[0];
    const float* emb_item = (const float*)d_in[1];
    const float* edge_val = (const float*)d_in[2];
    const int*   edge_row = (const int*)d_in[3];
    const int*   edge_col = (const int*)d_in[4];
    float* out = (float*)d_out;

    const size_t node_elems = (size_t)N_NODES * EMB;        // 19.2M floats
    char* ws = (char*)d_ws;

    // workspace layout (stage aliases bufB: dead until SpMM layer 0)
    const size_t off_bufA    = 0;
    const size_t off_bufB    = off_bufA + node_elems * sizeof(float);      // 76.8 MB
    const size_t off_packed  = off_bufB + node_elems * sizeof(float);      // 153.6 MB
    const size_t off_start   = off_packed + (size_t)N_EDGES * sizeof(Edge);// 193.6 MB
    const size_t off_cursor  = off_start + (N_NODES + 4) * sizeof(int);
    const size_t off_cnt     = off_cursor + N_NODES * sizeof(int);
    const size_t off_bsum    = off_cnt + N_NODES * sizeof(int);
    const size_t off_bpre    = off_bsum + SCAN_BLOCKS * sizeof(int);
    const size_t off_bcursor = off_bpre + SCAN_BLOCKS * sizeof(int);
    const size_t needed      = off_bcursor + (NBUCK + 4) * sizeof(int);    // ~197.2 MB

    float* bufA = (float*)(ws + off_bufA);
    float* bufB = (float*)(ws + off_bufB);

    const int nt4       = N_NODES * EMB / 4;
    const int el_blocks = (nt4 + 255) / 256;
    const int e_blocks  = (N_EDGES + 255) / 256;

    init_kernel<<<el_blocks, 256, 0, stream>>>(emb_user, emb_item, bufA, out);

    if (ws_size >= needed) {
        // ---- CSR path ----
        Edge*  packed  = (Edge*) (ws + off_packed);
        int*   start   = (int*)  (ws + off_start);
        int*   cursor  = (int*)  (ws + off_cursor);
        int*   cnt     = (int*)  (ws + off_cnt);
        int*   bsum    = (int*)  (ws + off_bsum);
        int*   bpre    = (int*)  (ws + off_bpre);
        int*   bcursor = (int*)  (ws + off_bcursor);
        Edge3* stage   = (Edge3*)(ws + off_bufB);   // 60 MB inside bufB

        hipMemsetAsync(cnt, 0, N_NODES * sizeof(int), stream);
        count_kernel<<<e_blocks, 256, 0, stream>>>(edge_row, cnt);
        bsum_kernel<<<SCAN_BLOCKS, 256, 0, stream>>>(cnt, bsum);
        bscan_kernel<<<1, 1024, 0, stream>>>(bsum, bpre);
        scan_apply_kernel<<<SCAN_BLOCKS, 256, 0, stream>>>(cnt, bpre, start, cursor);
        binit_kernel<<<1, 256, 0, stream>>>(start, bcursor);
        const int bin_blocks = (N_EDGES + BIN_CHUNK - 1) / BIN_CHUNK;      // 1221
        bin_kernel<<<bin_blocks, 256, 0, stream>>>(edge_row, edge_col, edge_val,
                                                   bcursor, stage);
        bscatter_kernel<<<e_blocks, 256, 0, stream>>>(stage, cursor, packed);

        const int row_blocks = (N_NODES + 15) / 16;          // 16 rows / block
        float* cur = bufA;
        float* nxt = bufB;
        for (int layer = 0; layer < 3; ++layer) {
            spmm_csr_kernel<<<row_blocks, 256, 0, stream>>>(
                cur, packed, start, cursor, nxt, out,
                (layer == 2) ? 0.25f : 1.0f);
            float* tmp = cur; cur = nxt; nxt = tmp;
        }
    } else {
        // ---- fallback: atomic path (needs only 153.6 MB) ----
        const int ew_blocks = (N_EDGES * 16 + 255) / 256;
        float* cur = bufA;
        float* nxt = bufB;
        for (int layer = 0; layer < 3; ++layer) {
            hipMemsetAsync(nxt, 0, node_elems * sizeof(float), stream);
            spmm_atomic_kernel<<<ew_blocks, 256, 0, stream>>>(
                cur, edge_val, edge_row, edge_col, nxt);
            addscale_kernel<<<el_blocks, 256, 0, stream>>>(
                nxt, out, (layer == 2) ? 0.25f : 1.0f);
            float* tmp = cur; cur = nxt; nxt = tmp;
        }
    }
}

// Round 5
// 1171.568 us; speedup vs baseline: 11.0078x; 1.1429x over previous
//
#include <hip/hip_runtime.h>

#define N_USERS 200000
#define N_ITEMS 100000
#define N_NODES 300000
#define EMB     64
#define N_EDGES 5000000

struct alignas(8) Edge  { int col; float val; };
struct Edge3 { int row; int col; float val; };   // 12 B staged record

// ---------------------------------------------------------------------------
// init: x = concat(emb_user, emb_item); out = x  (layer-sum seeded with x0)
// ---------------------------------------------------------------------------
__global__ __launch_bounds__(256) void init_kernel(
    const float* __restrict__ user, const float* __restrict__ item,
    float* __restrict__ x, float* __restrict__ out)
{
    const int nu4 = N_USERS * EMB / 4;
    const int nt4 = N_NODES * EMB / 4;
    int i = blockIdx.x * blockDim.x + threadIdx.x;
    if (i >= nt4) return;
    float4 v = (i < nu4) ? reinterpret_cast<const float4*>(user)[i]
                         : reinterpret_cast<const float4*>(item)[i - nu4];
    reinterpret_cast<float4*>(x)[i]   = v;
    reinterpret_cast<float4*>(out)[i] = v;
}

// ---------------------------------------------------------------------------
// CSR build step 1: per-row edge counts
// ---------------------------------------------------------------------------
__global__ __launch_bounds__(256) void count_kernel(
    const int* __restrict__ row, int* __restrict__ cnt)
{
    int e = blockIdx.x * blockDim.x + threadIdx.x;
    if (e < N_EDGES) atomicAdd(&cnt[row[e]], 1);
}

// ---------------------------------------------------------------------------
// CSR build step 2: hierarchical exclusive scan (3 phases, full-GPU parallel)
// ---------------------------------------------------------------------------
#define SCAN_BLOCKS ((N_NODES + 255) / 256)   // 1172

__global__ __launch_bounds__(256) void bsum_kernel(
    const int* __restrict__ cnt, int* __restrict__ bsum)
{
    __shared__ int s[256];
    int t = threadIdx.x;
    int i = blockIdx.x * 256 + t;
    s[t] = (i < N_NODES) ? cnt[i] : 0;
    __syncthreads();
    for (int ofs = 128; ofs > 0; ofs >>= 1) {
        if (t < ofs) s[t] += s[t + ofs];
        __syncthreads();
    }
    if (t == 0) bsum[blockIdx.x] = s[0];
}

__global__ __launch_bounds__(1024) void bscan_kernel(
    const int* __restrict__ bsum, int* __restrict__ bpre)
{
    __shared__ int s[1024];
    const int SEG = (SCAN_BLOCKS + 1023) / 1024;   // 2
    int t  = threadIdx.x;
    int lo = t * SEG;
    int hi = lo + SEG; if (hi > SCAN_BLOCKS) hi = SCAN_BLOCKS;
    int sum = 0;
    for (int i = lo; i < hi && i < SCAN_BLOCKS; ++i) sum += bsum[i];
    s[t] = sum;
    __syncthreads();
    for (int ofs = 1; ofs < 1024; ofs <<= 1) {
        int v = (t >= ofs) ? s[t - ofs] : 0;
        __syncthreads();
        s[t] += v;
        __syncthreads();
    }
    int running = s[t] - sum;
    for (int i = lo; i < hi && i < SCAN_BLOCKS; ++i) {
        bpre[i] = running;
        running += bsum[i];
    }
}

__global__ __launch_bounds__(256) void scan_apply_kernel(
    const int* __restrict__ cnt, const int* __restrict__ bpre,
    int* __restrict__ start)
{
    __shared__ int s[256];
    int t = threadIdx.x;
    int i = blockIdx.x * 256 + t;
    int v = (i < N_NODES) ? cnt[i] : 0;
    s[t] = v;
    __syncthreads();
    for (int ofs = 1; ofs < 256; ofs <<= 1) {
        int w = (t >= ofs) ? s[t - ofs] : 0;
        __syncthreads();
        s[t] += w;
        __syncthreads();
    }
    int excl = s[t] - v + bpre[blockIdx.x];
    if (i < N_NODES) start[i] = excl;
    if (blockIdx.x == 0 && t == 0) start[N_NODES] = N_EDGES;
}

// ---------------------------------------------------------------------------
// Two-phase bucketed scatter. Bucket = row >> 11 (2048 rows, 147 buckets).
// ---------------------------------------------------------------------------
#define BSHIFT 11
#define BROWS  (1 << BSHIFT)
#define NBUCK  ((N_NODES + BROWS - 1) >> BSHIFT)           // 147
#define BIN_EPT   16
#define BIN_BLK   256
#define BIN_CHUNK (BIN_BLK * BIN_EPT)                      // 4096 edges/block

__global__ __launch_bounds__(256) void binit_kernel(
    const int* __restrict__ start, int* __restrict__ bcursor)
{
    int t = threadIdx.x;
    if (t < NBUCK) {
        int lo = t << BSHIFT;
        if (lo > N_NODES) lo = N_NODES;
        bcursor[t] = start[lo];
    }
}

// phase 1: bin edges into bucket-contiguous staging (dense, line-friendly)
__global__ __launch_bounds__(256) void bin_kernel(
    const int* __restrict__ row, const int* __restrict__ col,
    const float* __restrict__ val, int* __restrict__ bcursor,
    Edge3* __restrict__ stage)
{
    __shared__ int hist[NBUCK];
    __shared__ int base[NBUCK];
    int t = threadIdx.x;
    long e0 = (long)blockIdx.x * BIN_CHUNK;

    int   r[BIN_EPT]; int c[BIN_EPT]; float v[BIN_EPT];
    for (int k = t; k < NBUCK; k += 256) hist[k] = 0;
    __syncthreads();

    int n = 0;
    #pragma unroll
    for (int k = 0; k < BIN_EPT; ++k) {
        long e = e0 + (long)k * BIN_BLK + t;
        if (e < N_EDGES) {
            r[k] = row[e]; c[k] = col[e]; v[k] = val[e];
            atomicAdd(&hist[r[k] >> BSHIFT], 1);
            n = k + 1;
        }
    }
    __syncthreads();
    for (int k = t; k < NBUCK; k += 256) {
        int h = hist[k];
        base[k] = h ? atomicAdd(&bcursor[k], h) : 0;
        hist[k] = 0;    // reuse as local cursor
    }
    __syncthreads();
    #pragma unroll
    for (int k = 0; k < BIN_EPT; ++k) {
        if (k < n) {
            long e = e0 + (long)k * BIN_BLK + t;
            if (e < N_EDGES) {
                int b   = r[k] >> BSHIFT;
                int pos = base[b] + atomicAdd(&hist[b], 1);
                Edge3 ed; ed.row = r[k]; ed.col = c[k]; ed.val = v[k];
                stage[pos] = ed;
            }
        }
    }
}

// phase 2: one WG per bucket. LDS row-cursors seeded from start[]; the
// ~273 KB destination window is written by exactly ONE CU -> lines merge in
// that XCD's L2; writeback ~= payload (fixes the 8-XCD false-sharing blowup).
__global__ __launch_bounds__(1024) void bucket_scatter_kernel(
    const Edge3* __restrict__ stage, const int* __restrict__ start,
    Edge* __restrict__ packed)
{
    __shared__ int cur[BROWS];
    int b    = blockIdx.x;
    int row0 = b << BSHIFT;
    int rows = N_NODES - row0; if (rows > BROWS) rows = BROWS;
    int t = threadIdx.x;

    for (int i = t; i < rows; i += 1024) cur[i] = start[row0 + i];
    __syncthreads();

    int ebeg = start[row0];
    int eend = start[row0 + rows];
    for (int e = ebeg + t; e < eend; e += 1024) {
        Edge3 ed = stage[e];
        int pos = atomicAdd(&cur[ed.row - row0], 1);
        Edge p; p.col = ed.col; p.val = ed.val;
        packed[pos] = p;
    }
}

// ---------------------------------------------------------------------------
// CSR SpMM, fused with layer-sum update.
// 16 lanes per row, 4 dims per lane, register accumulation, no atomics.
// Row end pointer = start[g+1] (exact CSR).
// ---------------------------------------------------------------------------
__global__ __launch_bounds__(256) void spmm_csr_kernel(
    const float* __restrict__ x, const Edge* __restrict__ packed,
    const int* __restrict__ start,
    float* __restrict__ y, float* __restrict__ out, float scale)
{
    int g = blockIdx.x * (256 / 16) + (threadIdx.x >> 4);
    if (g >= N_NODES) return;
    int d = (threadIdx.x & 15) * 4;

    int beg = start[g];
    int e   = start[g + 1];
    float4 acc = {0.f, 0.f, 0.f, 0.f};
    for (int j = beg; j < e; ++j) {
        Edge ed = packed[j];
        float4 xv = *reinterpret_cast<const float4*>(x + (size_t)ed.col * EMB + d);
        acc.x += ed.val * xv.x;
        acc.y += ed.val * xv.y;
        acc.z += ed.val * xv.z;
        acc.w += ed.val * xv.w;
    }
    *reinterpret_cast<float4*>(y + (size_t)g * EMB + d) = acc;

    float4 o = *reinterpret_cast<float4*>(out + (size_t)g * EMB + d);
    o.x = (o.x + acc.x) * scale;
    o.y = (o.y + acc.y) * scale;
    o.z = (o.z + acc.z) * scale;
    o.w = (o.w + acc.w) * scale;
    *reinterpret_cast<float4*>(out + (size_t)g * EMB + d) = o;
}

// ---------------------------------------------------------------------------
// Fallback path: edge-parallel atomics. Used only if ws too small for CSR.
// ---------------------------------------------------------------------------
__global__ __launch_bounds__(256) void spmm_atomic_kernel(
    const float* __restrict__ x, const float* __restrict__ val,
    const int* __restrict__ row, const int* __restrict__ col,
    float* __restrict__ y)
{
    int t = blockIdx.x * blockDim.x + threadIdx.x;
    int e = t >> 4;
    if (e >= N_EDGES) return;
    int d = (t & 15) * 4;
    int   r = row[e];
    int   c = col[e];
    float v = val[e];
    float4 xv = *reinterpret_cast<const float4*>(x + c * EMB + d);
    float* yp = y + r * EMB + d;
    unsafeAtomicAdd(yp + 0, v * xv.x);
    unsafeAtomicAdd(yp + 1, v * xv.y);
    unsafeAtomicAdd(yp + 2, v * xv.z);
    unsafeAtomicAdd(yp + 3, v * xv.w);
}

__global__ __launch_bounds__(256) void addscale_kernel(
    const float* __restrict__ xl, float* __restrict__ out, float scale)
{
    const int nt4 = N_NODES * EMB / 4;
    int i = blockIdx.x * blockDim.x + threadIdx.x;
    if (i >= nt4) return;
    float4 a = reinterpret_cast<float4*>(out)[i];
    float4 b = reinterpret_cast<const float4*>(xl)[i];
    a.x = (a.x + b.x) * scale;
    a.y = (a.y + b.y) * scale;
    a.z = (a.z + b.z) * scale;
    a.w = (a.w + b.w) * scale;
    reinterpret_cast<float4*>(out)[i] = a;
}

extern "C" void kernel_launch(void* const* d_in, const int* in_sizes, int n_in,
                              void* d_out, int out_size, void* d_ws, size_t ws_size,
                              hipStream_t stream) {
    const float* emb_user = (const float*)d_in[0];
    const float* emb_item = (const float*)d_in[1];
    const float* edge_val = (const float*)d_in[2];
    const int*   edge_row = (const int*)d_in[3];
    const int*   edge_col = (const int*)d_in[4];
    float* out = (float*)d_out;

    const size_t node_elems = (size_t)N_NODES * EMB;        // 19.2M floats
    char* ws = (char*)d_ws;

    // workspace layout (stage aliases bufB: dead until SpMM layer 0)
    const size_t off_bufA    = 0;
    const size_t off_bufB    = off_bufA + node_elems * sizeof(float);      // 76.8 MB
    const size_t off_packed  = off_bufB + node_elems * sizeof(float);      // 153.6 MB
    const size_t off_start   = off_packed + (size_t)N_EDGES * sizeof(Edge);// 193.6 MB
    const size_t off_cnt     = off_start + (N_NODES + 4) * sizeof(int);
    const size_t off_bsum    = off_cnt + N_NODES * sizeof(int);
    const size_t off_bpre    = off_bsum + SCAN_BLOCKS * sizeof(int);
    const size_t off_bcursor = off_bpre + SCAN_BLOCKS * sizeof(int);
    const size_t needed      = off_bcursor + (NBUCK + 4) * sizeof(int);    // ~196 MB

    float* bufA = (float*)(ws + off_bufA);
    float* bufB = (float*)(ws + off_bufB);

    const int nt4       = N_NODES * EMB / 4;
    const int el_blocks = (nt4 + 255) / 256;
    const int e_blocks  = (N_EDGES + 255) / 256;

    init_kernel<<<el_blocks, 256, 0, stream>>>(emb_user, emb_item, bufA, out);

    if (ws_size >= needed) {
        // ---- CSR path ----
        Edge*  packed  = (Edge*) (ws + off_packed);
        int*   start   = (int*)  (ws + off_start);
        int*   cnt     = (int*)  (ws + off_cnt);
        int*   bsum    = (int*)  (ws + off_bsum);
        int*   bpre    = (int*)  (ws + off_bpre);
        int*   bcursor = (int*)  (ws + off_bcursor);
        Edge3* stage   = (Edge3*)(ws + off_bufB);   // 60 MB inside bufB

        hipMemsetAsync(cnt, 0, N_NODES * sizeof(int), stream);
        count_kernel<<<e_blocks, 256, 0, stream>>>(edge_row, cnt);
        bsum_kernel<<<SCAN_BLOCKS, 256, 0, stream>>>(cnt, bsum);
        bscan_kernel<<<1, 1024, 0, stream>>>(bsum, bpre);
        scan_apply_kernel<<<SCAN_BLOCKS, 256, 0, stream>>>(cnt, bpre, start);
        binit_kernel<<<1, 256, 0, stream>>>(start, bcursor);
        const int bin_blocks = (N_EDGES + BIN_CHUNK - 1) / BIN_CHUNK;      // 1221
        bin_kernel<<<bin_blocks, 256, 0, stream>>>(edge_row, edge_col, edge_val,
                                                   bcursor, stage);
        bucket_scatter_kernel<<<NBUCK, 1024, 0, stream>>>(stage, start, packed);

        const int row_blocks = (N_NODES + 15) / 16;          // 16 rows / block
        float* cur = bufA;
        float* nxt = bufB;
        for (int layer = 0; layer < 3; ++layer) {
            spmm_csr_kernel<<<row_blocks, 256, 0, stream>>>(
                cur, packed, start, nxt, out,
                (layer == 2) ? 0.25f : 1.0f);
            float* tmp = cur; cur = nxt; nxt = tmp;
        }
    } else {
        // ---- fallback: atomic path (needs only 153.6 MB) ----
        const int ew_blocks = (N_EDGES * 16 + 255) / 256;
        float* cur = bufA;
        float* nxt = bufB;
        for (int layer = 0; layer < 3; ++layer) {
            hipMemsetAsync(nxt, 0, node_elems * sizeof(float), stream);
            spmm_atomic_kernel<<<ew_blocks, 256, 0, stream>>>(
                cur, edge_val, edge_row, edge_col, nxt);
            addscale_kernel<<<el_blocks, 256, 0, stream>>>(
                nxt, out, (layer == 2) ? 0.25f : 1.0f);
            float* tmp = cur; cur = nxt; nxt = tmp;
        }
    }
}